// Round 1
// baseline (909.407 us; speedup 1.0000x reference)
//
#include <hip/hip_runtime.h>

// GIN forward: 3x (scatter-add aggregate + MLP(BN,ReLU)) + pool + head.
// fp32 throughout. N=100000, E=1200000, DIM=64, G=1000, IN=11.

#define BN_EPS 1e-5f

// ---------------- scatter: out[dst[e]][d] += h[src[e]][d] ----------------
template<int D>
__global__ __launch_bounds__(256)
void scatter_add_kernel(const float* __restrict__ h,
                        const int* __restrict__ src,
                        const int* __restrict__ dst,
                        float* __restrict__ out,
                        long long total) {
    long long idx = (long long)blockIdx.x * 256 + threadIdx.x;
    if (idx >= total) return;
    int e = (int)(idx / D);
    int d = (int)(idx % D);
    int s = src[e], t = dst[e];
    atomicAdd(&out[(long long)t * D + d], h[(long long)s * D + d]);
}

// ---------------- fused per-node MLP: relu(bn(agg@wa+ba)) @ wb + bb, relu --
// 256 threads = 4 nodes x 64 lanes (lane = output feature).
template<int DIN>
__global__ __launch_bounds__(256)
void gin_mlp_kernel(const float* __restrict__ h_in,   // [n, DIN]
                    const float* __restrict__ scat,   // [n, DIN] (scatter sums)
                    const float* __restrict__ wa,     // [DIN,64]
                    const float* __restrict__ ba,     // [64]
                    const float* __restrict__ gam,    // [64]
                    const float* __restrict__ bet,    // [64]
                    const float* __restrict__ rm,     // [64]
                    const float* __restrict__ rv,     // [64]
                    const float* __restrict__ wb,     // [64,64]
                    const float* __restrict__ bb,     // [64]
                    float* __restrict__ h_out,        // [n,64]
                    int n) {
    __shared__ float s_wa[DIN * 64];
    __shared__ float s_wb[64 * 64];
    __shared__ float s_row[4][DIN];
    __shared__ float s_h1[4][64];

    const int tid   = threadIdx.x;
    const int lane  = tid & 63;
    const int local = tid >> 6;

    for (int i = tid; i < DIN * 64; i += 256) s_wa[i] = wa[i];
    for (int i = tid; i < 64 * 64; i += 256) s_wb[i] = wb[i];

    const float scale = gam[lane] * rsqrtf(rv[lane] + BN_EPS);
    const float shift = bet[lane] - rm[lane] * scale;
    const float ba_l  = ba[lane];
    const float bb_l  = bb[lane];
    __syncthreads();

    const int groups = (n + 3) >> 2;
    for (int grp = blockIdx.x; grp < groups; grp += gridDim.x) {
        const int node = grp * 4 + local;
        const bool ok = (node < n);
        if (ok && lane < DIN) {
            s_row[local][lane] = h_in[(long long)node * DIN + lane]
                               + scat[(long long)node * DIN + lane];
        }
        __syncthreads();
        if (ok) {
            float acc = ba_l;
            #pragma unroll
            for (int k = 0; k < DIN; ++k)
                acc = fmaf(s_row[local][k], s_wa[k * 64 + lane], acc);
            acc = fmaf(acc, scale, shift);   // BN (eval)
            acc = fmaxf(acc, 0.f);           // ReLU
            s_h1[local][lane] = acc;
        }
        __syncthreads();
        if (ok) {
            float acc = bb_l;
            #pragma unroll
            for (int k = 0; k < 64; ++k)
                acc = fmaf(s_h1[local][k], s_wb[k * 64 + lane], acc);
            acc = fmaxf(acc, 0.f);           // ReLU (extra h.relu() idempotent)
            h_out[(long long)node * 64 + lane] = acc;
        }
        __syncthreads();
    }
}

// ---------------- pool: hg[batch[i]] += h[i], batch sorted -----------------
// 64 threads (1 wave) per block, each block walks CHUNK nodes; lane = feature.
__global__ __launch_bounds__(64)
void pool_kernel(const float* __restrict__ h, const int* __restrict__ batch,
                 float* __restrict__ hg, int n) {
    const int CHUNK = 128;
    const int d = threadIdx.x;
    const int start = blockIdx.x * CHUNK;
    if (start >= n) return;
    const int end = min(start + CHUNK, n);
    float acc = 0.f;
    int cur = batch[start];
    for (int i = start; i < end; ++i) {
        int b = batch[i];
        if (b != cur) {
            atomicAdd(&hg[(long long)cur * 64 + d], acc);
            acc = 0.f;
            cur = b;
        }
        acc += h[(long long)i * 64 + d];
    }
    atomicAdd(&hg[(long long)cur * 64 + d], acc);
}

// ---------------- head: out = relu(hg@lw1+lb1) @ lw2 + lb2 -----------------
__global__ __launch_bounds__(256)
void head_kernel(const float* __restrict__ hg, const float* __restrict__ lw1,
                 const float* __restrict__ lb1, const float* __restrict__ lw2,
                 const float* __restrict__ lb2, float* __restrict__ out,
                 int ngraph) {
    __shared__ float s_w1[64 * 64];
    __shared__ float s_row[4][64];
    const int tid   = threadIdx.x;
    const int lane  = tid & 63;
    const int local = tid >> 6;
    for (int i = tid; i < 64 * 64; i += 256) s_w1[i] = lw1[i];
    const float b1 = lb1[lane];
    const float w2 = lw2[lane];
    const float b2 = lb2[0];
    __syncthreads();

    const int g = blockIdx.x * 4 + local;
    if (g < ngraph) s_row[local][lane] = hg[(long long)g * 64 + lane];
    __syncthreads();
    if (g < ngraph) {
        float acc = b1;
        #pragma unroll
        for (int k = 0; k < 64; ++k)
            acc = fmaf(s_row[local][k], s_w1[k * 64 + lane], acc);
        acc = fmaxf(acc, 0.f);
        float r = acc * w2;
        #pragma unroll
        for (int off = 32; off > 0; off >>= 1)
            r += __shfl_down(r, off, 64);
        if (lane == 0) out[g] = r + b2;
    }
}

extern "C" void kernel_launch(void* const* d_in, const int* in_sizes, int n_in,
                              void* d_out, int out_size, void* d_ws, size_t ws_size,
                              hipStream_t stream) {
    const float* x    = (const float*)d_in[0];
    const int* ei     = (const int*)d_in[1];
    const int* batch  = (const int*)d_in[2];
    const int N = in_sizes[0] / 11;
    const int E = in_sizes[1] / 2;
    const int G = out_size;
    const int* src = ei;
    const int* dst = ei + E;

    const float* p[28];
    for (int i = 0; i < 28; ++i) p[i] = (const float*)d_in[3 + i];
    // p[0..7]=layer1 {wa,ba,g,be,m,v,wb,bb}, p[8..15]=layer2, p[16..23]=layer3
    // p[24]=lw1 p[25]=lb1 p[26]=lw2 p[27]=lb2

    float* bufA = (float*)d_ws;                  // [N,64]
    float* bufB = bufA + (size_t)N * 64;         // [N,64]
    float* scat = bufB + (size_t)N * 64;         // [N,64] (layer1 uses N*11)
    float* hg   = scat + (size_t)N * 64;         // [G,64]

    // ---- layer 1 (DIN=11) ----
    hipMemsetAsync(scat, 0, (size_t)N * 11 * sizeof(float), stream);
    {
        long long tot = (long long)E * 11;
        int blocks = (int)((tot + 255) / 256);
        scatter_add_kernel<11><<<blocks, 256, 0, stream>>>(x, src, dst, scat, tot);
    }
    gin_mlp_kernel<11><<<4096, 256, 0, stream>>>(x, scat,
        p[0], p[1], p[2], p[3], p[4], p[5], p[6], p[7], bufA, N);

    // ---- layer 2 (DIN=64) ----
    hipMemsetAsync(scat, 0, (size_t)N * 64 * sizeof(float), stream);
    {
        long long tot = (long long)E * 64;
        int blocks = (int)((tot + 255) / 256);
        scatter_add_kernel<64><<<blocks, 256, 0, stream>>>(bufA, src, dst, scat, tot);
    }
    gin_mlp_kernel<64><<<4096, 256, 0, stream>>>(bufA, scat,
        p[8], p[9], p[10], p[11], p[12], p[13], p[14], p[15], bufB, N);

    // ---- layer 3 (DIN=64) ----
    hipMemsetAsync(scat, 0, (size_t)N * 64 * sizeof(float), stream);
    {
        long long tot = (long long)E * 64;
        int blocks = (int)((tot + 255) / 256);
        scatter_add_kernel<64><<<blocks, 256, 0, stream>>>(bufB, src, dst, scat, tot);
    }
    gin_mlp_kernel<64><<<4096, 256, 0, stream>>>(bufB, scat,
        p[16], p[17], p[18], p[19], p[20], p[21], p[22], p[23], bufA, N);

    // ---- pool ----
    hipMemsetAsync(hg, 0, (size_t)G * 64 * sizeof(float), stream);
    {
        int blocks = (N + 127) / 128;
        pool_kernel<<<blocks, 64, 0, stream>>>(bufA, batch, hg, N);
    }

    // ---- head ----
    head_kernel<<<(G + 3) / 4, 256, 0, stream>>>(hg,
        p[24], p[25], p[26], p[27], (float*)d_out, G);
}

// Round 2
// 599.915 us; speedup vs baseline: 1.5159x; 1.5159x over previous
//
#include <hip/hip_runtime.h>

// GIN forward, gather-based: CSR build (hist/scan/fill) + 3x fused
// (gather-aggregate + MLP(BN,ReLU)) + pool + head. fp32 throughout.
// N=100000, E=1200000, DIM=64, G=1000, IN=11.

#define BN_EPS 1e-5f

// ---------------- CSR build ----------------
__global__ __launch_bounds__(256)
void hist_kernel(const int* __restrict__ dst, int* __restrict__ deg, int E) {
    int e = blockIdx.x * 256 + threadIdx.x;
    if (e < E) atomicAdd(&deg[dst[e]], 1);
}

__global__ __launch_bounds__(256)
void scan_block_kernel(const int* __restrict__ deg, int* __restrict__ rp,
                       int* __restrict__ bsum, int n) {
    __shared__ int s[256];
    int i = blockIdx.x * 256 + threadIdx.x;
    int v = (i < n) ? deg[i] : 0;
    s[threadIdx.x] = v;
    __syncthreads();
    for (int off = 1; off < 256; off <<= 1) {
        int t = (threadIdx.x >= off) ? s[threadIdx.x - off] : 0;
        __syncthreads();
        s[threadIdx.x] += t;
        __syncthreads();
    }
    if (i < n) rp[i] = s[threadIdx.x] - v;              // block-local exclusive
    if (threadIdx.x == 255) bsum[blockIdx.x] = s[255];  // block total
}

__global__ __launch_bounds__(512)
void scan_top_kernel(int* bsum, int nb) {
    __shared__ int s[512];
    int v = (threadIdx.x < nb) ? bsum[threadIdx.x] : 0;
    s[threadIdx.x] = v;
    __syncthreads();
    for (int off = 1; off < 512; off <<= 1) {
        int t = (threadIdx.x >= off) ? s[threadIdx.x - off] : 0;
        __syncthreads();
        s[threadIdx.x] += t;
        __syncthreads();
    }
    if (threadIdx.x < nb) bsum[threadIdx.x] = s[threadIdx.x] - v;  // exclusive
}

__global__ __launch_bounds__(256)
void scan_add_kernel(int* __restrict__ rp, int* __restrict__ cursor,
                     const int* __restrict__ bsum, int n, int E) {
    int i = blockIdx.x * 256 + threadIdx.x;
    if (i < n) {
        int v = rp[i] + bsum[blockIdx.x];
        rp[i] = v;
        cursor[i] = v;
    }
    if (i == 0) rp[n] = E;
}

__global__ __launch_bounds__(256)
void fill_kernel(const int* __restrict__ src, const int* __restrict__ dst,
                 int* __restrict__ cursor, int* __restrict__ col, int E) {
    int e = blockIdx.x * 256 + threadIdx.x;
    if (e < E) {
        int pos = atomicAdd(&cursor[dst[e]], 1);
        col[pos] = src[e];
    }
}

// ------------- fused layer: gather + relu(bn(agg@wa+ba)) @ wb + bb, relu ---
// 256 threads = 4 nodes x 64 lanes (lane = output feature). s_row/s_h1 are
// wave-private -> no inner barriers needed.
template<int DIN>
__global__ __launch_bounds__(256)
void gin_layer_kernel(const float* __restrict__ h_in,   // [n, DIN]
                      const int* __restrict__ rp,       // [n+1]
                      const int* __restrict__ col,      // [E] src sorted by dst
                      const float* __restrict__ wa,     // [DIN,64]
                      const float* __restrict__ ba,     // [64]
                      const float* __restrict__ gam,    // [64]
                      const float* __restrict__ bet,    // [64]
                      const float* __restrict__ rm,     // [64]
                      const float* __restrict__ rv,     // [64]
                      const float* __restrict__ wb,     // [64,64]
                      const float* __restrict__ bb,     // [64]
                      float* __restrict__ h_out,        // [n,64]
                      int n) {
    __shared__ float s_wa[DIN * 64];
    __shared__ float s_wb[64 * 64];
    __shared__ float s_row[4][DIN];
    __shared__ float s_h1[4][64];

    const int tid   = threadIdx.x;
    const int lane  = tid & 63;
    const int local = tid >> 6;

    for (int i = tid; i < DIN * 64; i += 256) s_wa[i] = wa[i];
    for (int i = tid; i < 64 * 64; i += 256) s_wb[i] = wb[i];

    const float scale = gam[lane] * rsqrtf(rv[lane] + BN_EPS);
    const float shift = bet[lane] - rm[lane] * scale;
    const float ba_l  = ba[lane];
    const float bb_l  = bb[lane];
    __syncthreads();

    const int groups = (n + 3) >> 2;
    for (int grp = blockIdx.x; grp < groups; grp += gridDim.x) {
        const int node = grp * 4 + local;
        if (node >= n) continue;

        // gather-aggregate: self + sum of in-neighbors
        if (lane < DIN) {
            float agg = h_in[(long long)node * DIN + lane];
            int i = rp[node], end = rp[node + 1];
            for (; i + 1 < end; i += 2) {
                int c0 = col[i], c1 = col[i + 1];
                float a0 = h_in[(long long)c0 * DIN + lane];
                float a1 = h_in[(long long)c1 * DIN + lane];
                agg += a0;
                agg += a1;
            }
            if (i < end) agg += h_in[(long long)col[i] * DIN + lane];
            s_row[local][lane] = agg;
        }

        // GEMM1 + BN + ReLU (wave-private LDS, compiler inserts lgkmcnt)
        {
            float acc = ba_l;
            #pragma unroll
            for (int k = 0; k < DIN; ++k)
                acc = fmaf(s_row[local][k], s_wa[k * 64 + lane], acc);
            acc = fmaf(acc, scale, shift);
            acc = fmaxf(acc, 0.f);
            s_h1[local][lane] = acc;
        }
        // GEMM2 + ReLU
        {
            float acc = bb_l;
            #pragma unroll
            for (int k = 0; k < 64; ++k)
                acc = fmaf(s_h1[local][k], s_wb[k * 64 + lane], acc);
            acc = fmaxf(acc, 0.f);
            h_out[(long long)node * 64 + lane] = acc;
        }
    }
}

// ---------------- pool: hg[batch[i]] += h[i], batch sorted -----------------
__global__ __launch_bounds__(64)
void pool_kernel(const float* __restrict__ h, const int* __restrict__ batch,
                 float* __restrict__ hg, int n) {
    const int CHUNK = 128;
    const int d = threadIdx.x;
    const int start = blockIdx.x * CHUNK;
    if (start >= n) return;
    const int end = min(start + CHUNK, n);
    float acc = 0.f;
    int cur = batch[start];
    for (int i = start; i < end; ++i) {
        int b = batch[i];
        if (b != cur) {
            atomicAdd(&hg[(long long)cur * 64 + d], acc);
            acc = 0.f;
            cur = b;
        }
        acc += h[(long long)i * 64 + d];
    }
    atomicAdd(&hg[(long long)cur * 64 + d], acc);
}

// ---------------- head: out = relu(hg@lw1+lb1) @ lw2 + lb2 -----------------
__global__ __launch_bounds__(256)
void head_kernel(const float* __restrict__ hg, const float* __restrict__ lw1,
                 const float* __restrict__ lb1, const float* __restrict__ lw2,
                 const float* __restrict__ lb2, float* __restrict__ out,
                 int ngraph) {
    __shared__ float s_w1[64 * 64];
    __shared__ float s_row[4][64];
    const int tid   = threadIdx.x;
    const int lane  = tid & 63;
    const int local = tid >> 6;
    for (int i = tid; i < 64 * 64; i += 256) s_w1[i] = lw1[i];
    const float b1 = lb1[lane];
    const float w2 = lw2[lane];
    const float b2 = lb2[0];
    __syncthreads();

    const int g = blockIdx.x * 4 + local;
    if (g < ngraph) s_row[local][lane] = hg[(long long)g * 64 + lane];
    __syncthreads();
    if (g < ngraph) {
        float acc = b1;
        #pragma unroll
        for (int k = 0; k < 64; ++k)
            acc = fmaf(s_row[local][k], s_w1[k * 64 + lane], acc);
        acc = fmaxf(acc, 0.f);
        float r = acc * w2;
        #pragma unroll
        for (int off = 32; off > 0; off >>= 1)
            r += __shfl_down(r, off, 64);
        if (lane == 0) out[g] = r + b2;
    }
}

extern "C" void kernel_launch(void* const* d_in, const int* in_sizes, int n_in,
                              void* d_out, int out_size, void* d_ws, size_t ws_size,
                              hipStream_t stream) {
    const float* x    = (const float*)d_in[0];
    const int* ei     = (const int*)d_in[1];
    const int* batch  = (const int*)d_in[2];
    const int N = in_sizes[0] / 11;
    const int E = in_sizes[1] / 2;
    const int G = out_size;
    const int* src = ei;
    const int* dst = ei + E;

    const float* p[28];
    for (int i = 0; i < 28; ++i) p[i] = (const float*)d_in[3 + i];
    // p[0..7]=layer1 {wa,ba,g,be,m,v,wb,bb}, p[8..15]=layer2, p[16..23]=layer3
    // p[24]=lw1 p[25]=lb1 p[26]=lw2 p[27]=lb2

    float* bufA  = (float*)d_ws;                  // [N,64]
    float* bufB  = bufA + (size_t)N * 64;         // [N,64]
    int*   deg   = (int*)(bufB + (size_t)N * 64); // [N]
    int*   rp    = deg + N;                       // [N+1]
    int*   cursor= rp + N + 1;                    // [N]
    int*   bsum  = cursor + N;                    // [512]
    int*   col   = bsum + 512;                    // [E]
    float* hg    = (float*)(col + E);             // [G,64]

    const int nbScan = (N + 255) / 256;           // 391 (< 512)
    const int nbE    = (E + 255) / 256;

    // ---- CSR build (by dst) ----
    hipMemsetAsync(deg, 0, (size_t)N * sizeof(int), stream);
    hist_kernel<<<nbE, 256, 0, stream>>>(dst, deg, E);
    scan_block_kernel<<<nbScan, 256, 0, stream>>>(deg, rp, bsum, N);
    scan_top_kernel<<<1, 512, 0, stream>>>(bsum, nbScan);
    scan_add_kernel<<<nbScan, 256, 0, stream>>>(rp, cursor, bsum, N, E);
    fill_kernel<<<nbE, 256, 0, stream>>>(src, dst, cursor, col, E);

    // ---- layers ----
    gin_layer_kernel<11><<<4096, 256, 0, stream>>>(x, rp, col,
        p[0], p[1], p[2], p[3], p[4], p[5], p[6], p[7], bufA, N);
    gin_layer_kernel<64><<<4096, 256, 0, stream>>>(bufA, rp, col,
        p[8], p[9], p[10], p[11], p[12], p[13], p[14], p[15], bufB, N);
    gin_layer_kernel<64><<<4096, 256, 0, stream>>>(bufB, rp, col,
        p[16], p[17], p[18], p[19], p[20], p[21], p[22], p[23], bufA, N);

    // ---- pool ----
    hipMemsetAsync(hg, 0, (size_t)G * 64 * sizeof(float), stream);
    pool_kernel<<<(N + 127) / 128, 64, 0, stream>>>(bufA, batch, hg, N);

    // ---- head ----
    head_kernel<<<(G + 3) / 4, 256, 0, stream>>>(hg,
        p[24], p[25], p[26], p[27], (float*)d_out, G);
}

// Round 3
// 580.511 us; speedup vs baseline: 1.5666x; 1.0334x over previous
//
#include <hip/hip_runtime.h>

// GIN forward, split gather/compute with transformed-space aggregation:
// y = h @ wa  (linearity: agg@wa = y_self + sum y_neighbors)
// CSR build + pre-transform + 3x (agg64 + MLP[BN,ReLU,@wb,ReLU,@wa_next])
// + pool + head. fp32 throughout. N=100000, E=1200000, DIM=64, G=1000, IN=11.

#define BN_EPS 1e-5f

// ---------------- CSR build ----------------
__global__ __launch_bounds__(256)
void hist_kernel(const int* __restrict__ dst, int* __restrict__ deg, int E) {
    int e = blockIdx.x * 256 + threadIdx.x;
    if (e < E) atomicAdd(&deg[dst[e]], 1);
}

__global__ __launch_bounds__(256)
void scan_block_kernel(const int* __restrict__ deg, int* __restrict__ rp,
                       int* __restrict__ bsum, int n) {
    __shared__ int s[256];
    int i = blockIdx.x * 256 + threadIdx.x;
    int v = (i < n) ? deg[i] : 0;
    s[threadIdx.x] = v;
    __syncthreads();
    for (int off = 1; off < 256; off <<= 1) {
        int t = (threadIdx.x >= off) ? s[threadIdx.x - off] : 0;
        __syncthreads();
        s[threadIdx.x] += t;
        __syncthreads();
    }
    if (i < n) rp[i] = s[threadIdx.x] - v;
    if (threadIdx.x == 255) bsum[blockIdx.x] = s[255];
}

__global__ __launch_bounds__(512)
void scan_top_kernel(int* bsum, int nb) {
    __shared__ int s[512];
    int v = (threadIdx.x < nb) ? bsum[threadIdx.x] : 0;
    s[threadIdx.x] = v;
    __syncthreads();
    for (int off = 1; off < 512; off <<= 1) {
        int t = (threadIdx.x >= off) ? s[threadIdx.x - off] : 0;
        __syncthreads();
        s[threadIdx.x] += t;
        __syncthreads();
    }
    if (threadIdx.x < nb) bsum[threadIdx.x] = s[threadIdx.x] - v;
}

__global__ __launch_bounds__(256)
void scan_add_kernel(int* __restrict__ rp, int* __restrict__ cursor,
                     const int* __restrict__ bsum, int n, int E) {
    int i = blockIdx.x * 256 + threadIdx.x;
    if (i < n) {
        int v = rp[i] + bsum[blockIdx.x];
        rp[i] = v;
        cursor[i] = v;
    }
    if (i == 0) rp[n] = E;
}

__global__ __launch_bounds__(256)
void fill_kernel(const int* __restrict__ src, const int* __restrict__ dst,
                 int* __restrict__ cursor, int* __restrict__ col, int E) {
    int e = blockIdx.x * 256 + threadIdx.x;
    if (e < E) {
        int pos = atomicAdd(&cursor[dst[e]], 1);
        col[pos] = src[e];
    }
}

// ---------------- pre-transform: y = x @ w1a (no bias) ----------------
__global__ __launch_bounds__(256)
void pre_kernel(const float* __restrict__ x, const float* __restrict__ wa,
                float* __restrict__ y, int n) {
    __shared__ float s_wa[11 * 64];
    __shared__ float s_row[4][11];
    const int tid = threadIdx.x;
    const int lane = tid & 63;
    const int local = tid >> 6;
    for (int i = tid; i < 11 * 64; i += 256) s_wa[i] = wa[i];
    __syncthreads();
    const int groups = (n + 3) >> 2;
    for (int grp = blockIdx.x; grp < groups; grp += gridDim.x) {
        const int node = grp * 4 + local;
        if (node >= n) continue;
        if (lane < 11) s_row[local][lane] = x[(size_t)node * 11 + lane];
        float acc = 0.f;
        #pragma unroll
        for (int k = 0; k < 11; ++k)
            acc = fmaf(s_row[local][k], s_wa[k * 64 + lane], acc);
        y[(size_t)node * 64 + lane] = acc;
    }
}

// ------------- aggregate (64-dim): a[i] = y[i] + sum_{j->i} y[j] -----------
// wave = node, lane = feature; no LDS -> max occupancy; 4-deep gather.
__global__ __launch_bounds__(256)
void agg_kernel(const float* __restrict__ y, const int* __restrict__ rp,
                const int* __restrict__ col, float* __restrict__ out, int n) {
    const int node = (blockIdx.x * 256 + threadIdx.x) >> 6;
    if (node >= n) return;
    const int lane = threadIdx.x & 63;
    const int beg = rp[node], end = rp[node + 1];
    float agg = y[(size_t)node * 64 + lane];
    int i = beg;
    for (; i + 4 <= end; i += 4) {
        int c0 = col[i], c1 = col[i + 1], c2 = col[i + 2], c3 = col[i + 3];
        float v0 = y[(size_t)c0 * 64 + lane];
        float v1 = y[(size_t)c1 * 64 + lane];
        float v2 = y[(size_t)c2 * 64 + lane];
        float v3 = y[(size_t)c3 * 64 + lane];
        agg += v0; agg += v1; agg += v2; agg += v3;
    }
    for (; i < end; ++i) agg += y[(size_t)col[i] * 64 + lane];
    out[(size_t)node * 64 + lane] = agg;
}

// ------------- MLP: t=relu(bn(a+ba)); z=relu(t@wb+bb); y'=z@wa_next --------
// LAST: write z (=h3) instead. Streaming, wave-private tiles, no inner bars.
template<bool LAST>
__global__ __launch_bounds__(256)
void mlp_kernel(const float* __restrict__ a,     // [n,64] aggregated y
                const float* __restrict__ ba,    // [64] deferred lin-a bias
                const float* __restrict__ gam, const float* __restrict__ bet,
                const float* __restrict__ rm, const float* __restrict__ rv,
                const float* __restrict__ wb,    // [64,64]
                const float* __restrict__ bb,    // [64]
                const float* __restrict__ wn,    // [64,64] next wa (or null)
                float* __restrict__ out,         // [n,64]
                int n) {
    __shared__ float s_wb[64 * 64];
    __shared__ float s_wn[LAST ? 64 : 64 * 64];
    __shared__ float s_t[4][64];
    __shared__ float s_z[4][64];

    const int tid = threadIdx.x;
    const int lane = tid & 63;
    const int local = tid >> 6;

    for (int i = tid; i < 64 * 64; i += 256) s_wb[i] = wb[i];
    if (!LAST) for (int i = tid; i < 64 * 64; i += 256) s_wn[i] = wn[i];

    const float scale = gam[lane] * rsqrtf(rv[lane] + BN_EPS);
    const float shift = bet[lane] - rm[lane] * scale;
    const float ba_l = ba[lane];
    const float bb_l = bb[lane];
    __syncthreads();

    const int groups = (n + 3) >> 2;
    for (int grp = blockIdx.x; grp < groups; grp += gridDim.x) {
        const int node = grp * 4 + local;
        if (node >= n) continue;
        {
            float t = a[(size_t)node * 64 + lane] + ba_l;
            t = fmaf(t, scale, shift);
            t = fmaxf(t, 0.f);
            s_t[local][lane] = t;
        }
        {
            float acc = bb_l;
            #pragma unroll
            for (int k = 0; k < 64; ++k)
                acc = fmaf(s_t[local][k], s_wb[k * 64 + lane], acc);
            acc = fmaxf(acc, 0.f);
            if (LAST) {
                out[(size_t)node * 64 + lane] = acc;
            } else {
                s_z[local][lane] = acc;
            }
        }
        if (!LAST) {
            float acc = 0.f;
            #pragma unroll
            for (int k = 0; k < 64; ++k)
                acc = fmaf(s_z[local][k], s_wn[k * 64 + lane], acc);
            out[(size_t)node * 64 + lane] = acc;
        }
    }
}

// ---------------- pool: hg[batch[i]] += h[i], batch sorted -----------------
__global__ __launch_bounds__(64)
void pool_kernel(const float* __restrict__ h, const int* __restrict__ batch,
                 float* __restrict__ hg, int n) {
    const int CHUNK = 128;
    const int d = threadIdx.x;
    const int start = blockIdx.x * CHUNK;
    if (start >= n) return;
    const int end = min(start + CHUNK, n);
    float acc = 0.f;
    int cur = batch[start];
    for (int i = start; i < end; ++i) {
        int b = batch[i];
        if (b != cur) {
            atomicAdd(&hg[(size_t)cur * 64 + d], acc);
            acc = 0.f;
            cur = b;
        }
        acc += h[(size_t)i * 64 + d];
    }
    atomicAdd(&hg[(size_t)cur * 64 + d], acc);
}

// ---------------- head: out = relu(hg@lw1+lb1) @ lw2 + lb2 -----------------
__global__ __launch_bounds__(256)
void head_kernel(const float* __restrict__ hg, const float* __restrict__ lw1,
                 const float* __restrict__ lb1, const float* __restrict__ lw2,
                 const float* __restrict__ lb2, float* __restrict__ out,
                 int ngraph) {
    __shared__ float s_w1[64 * 64];
    __shared__ float s_row[4][64];
    const int tid = threadIdx.x;
    const int lane = tid & 63;
    const int local = tid >> 6;
    for (int i = tid; i < 64 * 64; i += 256) s_w1[i] = lw1[i];
    const float b1 = lb1[lane];
    const float w2 = lw2[lane];
    const float b2 = lb2[0];
    __syncthreads();

    const int g = blockIdx.x * 4 + local;
    if (g < ngraph) s_row[local][lane] = hg[(size_t)g * 64 + lane];
    __syncthreads();
    if (g < ngraph) {
        float acc = b1;
        #pragma unroll
        for (int k = 0; k < 64; ++k)
            acc = fmaf(s_row[local][k], s_w1[k * 64 + lane], acc);
        acc = fmaxf(acc, 0.f);
        float r = acc * w2;
        #pragma unroll
        for (int off = 32; off > 0; off >>= 1)
            r += __shfl_down(r, off, 64);
        if (lane == 0) out[g] = r + b2;
    }
}

extern "C" void kernel_launch(void* const* d_in, const int* in_sizes, int n_in,
                              void* d_out, int out_size, void* d_ws, size_t ws_size,
                              hipStream_t stream) {
    const float* x    = (const float*)d_in[0];
    const int* ei     = (const int*)d_in[1];
    const int* batch  = (const int*)d_in[2];
    const int N = in_sizes[0] / 11;
    const int E = in_sizes[1] / 2;
    const int G = out_size;
    const int* src = ei;
    const int* dst = ei + E;

    const float* p[28];
    for (int i = 0; i < 28; ++i) p[i] = (const float*)d_in[3 + i];
    // p[0..7]=L1 {wa,ba,g,be,m,v,wb,bb}, p[8..15]=L2, p[16..23]=L3
    // p[24]=lw1 p[25]=lb1 p[26]=lw2 p[27]=lb2

    float* y     = (float*)d_ws;                   // [N,64] transformed feats
    float* aggb  = y + (size_t)N * 64;             // [N,64]
    float* y2    = aggb + (size_t)N * 64;          // [N,64] next / h3
    int*   deg   = (int*)(y2 + (size_t)N * 64);    // [N]
    int*   rp    = deg + N;                        // [N+1]
    int*   cursor= rp + N + 1;                     // [N]
    int*   bsum  = cursor + N;                     // [512]
    int*   col   = bsum + 512;                     // [E]
    float* hg    = (float*)(col + E);              // [G,64]

    const int nbScan = (N + 255) / 256;
    const int nbE    = (E + 255) / 256;
    const int nbNode = (N * 64 + 255) / 256;       // exact, wave=node

    // ---- CSR build (by dst) ----
    hipMemsetAsync(deg, 0, (size_t)N * sizeof(int), stream);
    hist_kernel<<<nbE, 256, 0, stream>>>(dst, deg, E);
    scan_block_kernel<<<nbScan, 256, 0, stream>>>(deg, rp, bsum, N);
    scan_top_kernel<<<1, 512, 0, stream>>>(bsum, nbScan);
    scan_add_kernel<<<nbScan, 256, 0, stream>>>(rp, cursor, bsum, N, E);
    fill_kernel<<<nbE, 256, 0, stream>>>(src, dst, cursor, col, E);

    // ---- pre-transform y1 = x @ w1a ----
    pre_kernel<<<2048, 256, 0, stream>>>(x, p[0], y, N);

    // ---- layer 1 ----
    agg_kernel<<<nbNode, 256, 0, stream>>>(y, rp, col, aggb, N);
    mlp_kernel<false><<<2048, 256, 0, stream>>>(aggb, p[1], p[2], p[3], p[4],
        p[5], p[6], p[7], p[8], y, N);             // y <- y2-space feats
    // ---- layer 2 ----
    agg_kernel<<<nbNode, 256, 0, stream>>>(y, rp, col, aggb, N);
    mlp_kernel<false><<<2048, 256, 0, stream>>>(aggb, p[9], p[10], p[11], p[12],
        p[13], p[14], p[15], p[16], y, N);         // y <- y3-space feats
    // ---- layer 3 ----
    agg_kernel<<<nbNode, 256, 0, stream>>>(y, rp, col, aggb, N);
    mlp_kernel<true><<<2048, 256, 0, stream>>>(aggb, p[17], p[18], p[19], p[20],
        p[21], p[22], p[23], nullptr, y2, N);      // y2 = h3

    // ---- pool ----
    hipMemsetAsync(hg, 0, (size_t)G * 64 * sizeof(float), stream);
    pool_kernel<<<(N + 127) / 128, 64, 0, stream>>>(y2, batch, hg, N);

    // ---- head ----
    head_kernel<<<(G + 3) / 4, 256, 0, stream>>>(hg,
        p[24], p[25], p[26], p[27], (float*)d_out, G);
}